// Round 6
// baseline (146.422 us; speedup 1.0000x reference)
//
#include <hip/hip_runtime.h>
#include <hip/hip_bf16.h>

typedef __attribute__((ext_vector_type(4)))  float f32x4;
typedef __attribute__((ext_vector_type(16))) float f32x16;
typedef __bf16 bf16x8 __attribute__((ext_vector_type(8)));
typedef __attribute__((ext_vector_type(4))) unsigned int u32x4;

#define MFMA16(a, b, c) __builtin_amdgcn_mfma_f32_16x16x32_bf16((a), (b), (c), 0, 0, 0)
#define MFMA32(a, b, c) __builtin_amdgcn_mfma_f32_32x32x16_bf16((a), (b), (c), 0, 0, 0)

#define LOG2E 1.4426950408889634f

static __device__ inline unsigned pk2(float a, float b) {
    unsigned short ua = __builtin_bit_cast(unsigned short, (__bf16)a);
    unsigned short ub = __builtin_bit_cast(unsigned short, (__bf16)b);
    return (unsigned)ua | ((unsigned)ub << 16);
}

// v_permlane32_swap_b32: x' = {x_low, y_low}, y' = {x_high, y_high}
static __device__ inline void plswap(unsigned& x, unsigned& y) {
#if __has_builtin(__builtin_amdgcn_permlane32_swap)
    auto r = __builtin_amdgcn_permlane32_swap((int)x, (int)y, false, false);
    x = (unsigned)r[0];
    y = (unsigned)r[1];
#else
    unsigned ox = (unsigned)__shfl_xor((int)x, 32);
    unsigned oy = (unsigned)__shfl_xor((int)y, 32);
    const bool lo = ((threadIdx.x & 63) < 32);
    unsigned nx = lo ? x : oy;
    unsigned ny = lo ? ox : y;
    x = nx; y = ny;
#endif
}

// async global -> LDS, 16B per lane. LDS dest: wave-uniform base + lane*16.
static __device__ inline void gll16(const void* g, void* l) {
    __builtin_amdgcn_global_load_lds(
        (const __attribute__((address_space(1))) void*)g,
        (__attribute__((address_space(3))) void*)l, 16, 0, 0);
}

// ---------------------------------------------------------------------------
// Kernel 1: QKV projection. Y = X @ W^T + b, output bf16 in [bh][s][64].
// Q scaled by 0.125*log2e (score scale + exp2 domain).
// ---------------------------------------------------------------------------
__global__ __launch_bounds__(256) void qkv_gemm(
    const float* __restrict__ X,
    const float* __restrict__ Wq, const float* __restrict__ bq,
    const float* __restrict__ Wk, const float* __restrict__ bk,
    const float* __restrict__ Wv, const float* __restrict__ bv,
    __bf16* __restrict__ Qb, __bf16* __restrict__ Kb, __bf16* __restrict__ Vb)
{
    const int z = blockIdx.z;
    const float* W    = (z == 0) ? Wq : (z == 1) ? Wk : Wv;
    const float* bias = (z == 0) ? bq : (z == 1) ? bk : bv;
    __bf16* Ob        = (z == 0) ? Qb : (z == 1) ? Kb : Vb;
    const float oscale = (z == 0) ? (0.125f * LOG2E) : 1.0f;

    const int row0 = blockIdx.x * 128;
    const int col0 = blockIdx.y * 128;

    __shared__ __align__(16) __bf16 As[128 * 32];
    __shared__ __align__(16) __bf16 Bs[128 * 32];

    const int t    = threadIdx.x;
    const int lane = t & 63;
    const int w    = t >> 6;
    const int wr   = w >> 1, wc = w & 1;
    const int l15  = lane & 15, g = lane >> 4;

    f32x4 zero = {0.f, 0.f, 0.f, 0.f};
    f32x4 acc[4][4];
    #pragma unroll
    for (int m = 0; m < 4; ++m)
        #pragma unroll
        for (int n = 0; n < 4; ++n) acc[m][n] = zero;

    const int srow = t >> 1;
    const int scol = (t & 1) * 16;
    const float* ga = X + (size_t)(row0 + srow) * 1024 + scol;
    const float* gb = W + (size_t)(col0 + srow) * 1024 + scol;
    __bf16* la = As + srow * 32 + scol;
    __bf16* lb = Bs + srow * 32 + scol;

    for (int k0 = 0; k0 < 1024; k0 += 32) {
        f32x4 av[4], bw[4];
        #pragma unroll
        for (int q = 0; q < 4; ++q) av[q] = *reinterpret_cast<const f32x4*>(ga + k0 + q * 4);
        #pragma unroll
        for (int q = 0; q < 4; ++q) bw[q] = *reinterpret_cast<const f32x4*>(gb + k0 + q * 4);

        __syncthreads();

        bf16x8 pa0, pa1, pb0, pb1;
        #pragma unroll
        for (int j = 0; j < 4; ++j) {
            pa0[j] = (__bf16)av[0][j];  pa0[4 + j] = (__bf16)av[1][j];
            pa1[j] = (__bf16)av[2][j];  pa1[4 + j] = (__bf16)av[3][j];
            pb0[j] = (__bf16)bw[0][j];  pb0[4 + j] = (__bf16)bw[1][j];
            pb1[j] = (__bf16)bw[2][j];  pb1[4 + j] = (__bf16)bw[3][j];
        }
        *reinterpret_cast<bf16x8*>(la)     = pa0;
        *reinterpret_cast<bf16x8*>(la + 8) = pa1;
        *reinterpret_cast<bf16x8*>(lb)     = pb0;
        *reinterpret_cast<bf16x8*>(lb + 8) = pb1;

        __syncthreads();

        bf16x8 af[4], bf[4];
        const int kk = g * 8;
        #pragma unroll
        for (int m = 0; m < 4; ++m)
            af[m] = *reinterpret_cast<const bf16x8*>(As + (wr * 64 + m * 16 + l15) * 32 + kk);
        #pragma unroll
        for (int n = 0; n < 4; ++n)
            bf[n] = *reinterpret_cast<const bf16x8*>(Bs + (wc * 64 + n * 16 + l15) * 32 + kk);

        #pragma unroll
        for (int m = 0; m < 4; ++m)
            #pragma unroll
            for (int n = 0; n < 4; ++n)
                acc[m][n] = MFMA16(af[m], bf[n], acc[m][n]);
    }

    #pragma unroll
    for (int n = 0; n < 4; ++n) {
        const int e  = col0 + wc * 64 + n * 16 + l15;
        const float bv_ = bias[e];
        const int h = e >> 6, hd = e & 63;
        #pragma unroll
        for (int m = 0; m < 4; ++m) {
            #pragma unroll
            for (int j = 0; j < 4; ++j) {
                const int tok = row0 + wr * 64 + m * 16 + g * 4 + j;
                const int b = tok >> 11, s = tok & 2047;
                const int bh = b * 16 + h;
                Ob[((size_t)(bh * 2048 + s) << 6) | hd] =
                    (__bf16)((acc[m][n][j] + bv_) * oscale);
            }
        }
    }
}

// ---------------------------------------------------------------------------
// Kernel 2: V [bh][s][64] -> Vt [bh][64][s]
// ---------------------------------------------------------------------------
__global__ __launch_bounds__(256) void v_transpose(
    const __bf16* __restrict__ V, __bf16* __restrict__ Vt)
{
    __shared__ __align__(16) __bf16 T[64 * 72];
    const int t  = threadIdx.x;
    const int bh = blockIdx.y;
    const int s0 = blockIdx.x * 64;
    const int r  = t >> 2, q = t & 3;

    const __bf16* src = V + ((size_t)(bh * 2048 + s0 + r) << 6) + q * 16;
    bf16x8 v0 = *reinterpret_cast<const bf16x8*>(src);
    bf16x8 v1 = *reinterpret_cast<const bf16x8*>(src + 8);
    #pragma unroll
    for (int i = 0; i < 8; ++i) {
        T[(q * 16 + i) * 72 + r]     = v0[i];
        T[(q * 16 + 8 + i) * 72 + r] = v1[i];
    }
    __syncthreads();
    const int d = r, sc = q * 16;
    bf16x8 o0 = *reinterpret_cast<const bf16x8*>(&T[d * 72 + sc]);
    bf16x8 o1 = *reinterpret_cast<const bf16x8*>(&T[d * 72 + sc + 8]);
    __bf16* dst = Vt + ((size_t)(bh * 64 + d) << 11) + s0 + sc;
    *reinterpret_cast<bf16x8*>(dst)     = o0;
    *reinterpret_cast<bf16x8*>(dst + 8) = o1;
}

// ---------------------------------------------------------------------------
// Kernel 3: flash attention, FAT-WAVE: 64 q-rows per wave (two 32-q column
// blocks A/B sharing the K/V fragments) -> LDS-read per unit work halved,
// 2 softmax streams give intra-wave ILP. 2 waves/block, 512 blocks,
// 1 wave/SIMD with up to 512 VGPRs (launch_bounds(128,1)).
// K/V LDS double-buffer via global_load_lds, XOR-swizzled both-sides.
// ---------------------------------------------------------------------------
__global__ __launch_bounds__(128, 1) void flash_attn(
    const __bf16* __restrict__ Qb, const __bf16* __restrict__ Kb,
    const __bf16* __restrict__ Vt, const float* __restrict__ mask,
    float* __restrict__ out)
{
    // XCD swizzle: 512 blocks -> 64/XCD -> 4 bh per XCD L2 (2MB K+V)
    const int bid = blockIdx.x;
    const int wid = (bid & 7) * 64 + (bid >> 3);
    const int qt  = wid & 15;         // q-tile of 128 rows (2 waves * 64)
    const int bh  = wid >> 4;
    const int b = bh >> 4, h = bh & 15;

    const int t = threadIdx.x;        // 0..127
    const int lane = t & 63;
    const int w = t >> 6;             // 0,1
    const int l31 = lane & 31, hi = lane >> 5;
    const int qA = qt * 128 + w * 64 + l31;    // q-block A row
    // q-block B row = qA + 32

    __shared__ __align__(16) char KV[2][16384];   // [buf][K 8KB | V 8KB]
    __shared__ __align__(16) float mLs[2048];

    // ---- stage mask * log2e into LDS (128 threads x 16 floats)
    {
        const float* mb = mask + b * 2048 + t * 16;
        #pragma unroll
        for (int i = 0; i < 4; ++i) {
            f32x4 m0 = *reinterpret_cast<const f32x4*>(mb + i * 4);
            *reinterpret_cast<f32x4*>(&mLs[t * 16 + i * 4]) = m0 * LOG2E;
        }
    }

    // loop-invariant Q B-fragments for both q-blocks
    bf16x8 qfA[4], qfB[4];
    {
        const __bf16* qp = Qb + ((size_t)(bh * 2048 + qA) << 6) + hi * 8;
        #pragma unroll
        for (int ds = 0; ds < 4; ++ds) {
            qfA[ds] = *reinterpret_cast<const bf16x8*>(qp + ds * 16);
            qfB[ds] = *reinterpret_cast<const bf16x8*>(qp + 2048 + ds * 16);  // +32 rows
        }
    }

    f32x16 cA0, cA1, cB0, cB1;
    #pragma unroll
    for (int r = 0; r < 16; ++r) { cA0[r] = 0.f; cA1[r] = 0.f; cB0[r] = 0.f; cB1[r] = 0.f; }
    float mA = -1e30f, lA = 0.f, mB = -1e30f, lB = 0.f;

    // ---- staging precompute. LDS slot x: row = x>>7, swz s(x)=((row&7)<<4);
    // linear LDS dest + inverse-swizzled global src + swizzled ds_read.
    const char* Kbase = (const char*)(Kb + ((size_t)bh << 17));
    const char* Vbase = (const char*)(Vt + ((size_t)bh << 17));
    const char* srcK[4];
    const char* srcV[4];
    #pragma unroll
    for (int s = 0; s < 4; ++s) {
        const int x = s * 2048 + w * 1024 + lane * 16;   // region-local slot
        srcK[s] = Kbase + (x ^ (((x >> 7) & 7) << 4));
        srcV[s] = Vbase + (size_t)(x >> 7) * 4096
                        + ((x & 127) ^ (((x >> 7) & 7) << 4));
    }

    auto stage = [&](int buf, int kt) {
        char* L = &KV[buf][0];
        const size_t ko = (size_t)kt * 8192;
        const size_t vo = (size_t)kt * 128;
        #pragma unroll
        for (int s = 0; s < 4; ++s) {
            gll16(srcK[s] + ko, L + s * 2048 + w * 1024);
            gll16(srcV[s] + vo, L + 8192 + s * 2048 + w * 1024);
        }
    };

    const int swz = (l31 & 7) << 4;
    const int cb  = hi * 16;

    auto packP = [&](const f32x16& P0, const f32x16& P1, bf16x8 (&pb)[4]) {
        #pragma unroll
        for (int ks = 0; ks < 4; ++ks) {
            const f32x16& P = (ks < 2) ? P0 : P1;
            const int base = 8 * (ks & 1);
            unsigned a0 = pk2(P[base + 0], P[base + 1]);
            unsigned b0 = pk2(P[base + 4], P[base + 5]);
            unsigned a1 = pk2(P[base + 2], P[base + 3]);
            unsigned b1 = pk2(P[base + 6], P[base + 7]);
            plswap(a0, b0);
            plswap(a1, b1);
            u32x4 wv = {a0, a1, b0, b1};
            pb[ks] = __builtin_bit_cast(bf16x8, wv);
        }
    };

    auto compute = [&](int buf, int kbase) {
        const char* KB = &KV[buf][0];
        // ---- K fragments (swizzled ds_read_b128), shared by both q-blocks
        bf16x8 kc[8];
        #pragma unroll
        for (int ds = 0; ds < 4; ++ds) {
            const int c = (ds * 32 + cb) ^ swz;
            kc[ds]     = *reinterpret_cast<const bf16x8*>(KB + l31 * 128 + c);
            kc[4 + ds] = *reinterpret_cast<const bf16x8*>(KB + (32 + l31) * 128 + c);
        }

        // ---- scores init = mask (log2 domain); reg r=4c+j -> k = j+8c+4hi
        f32x16 pA0, pA1, pB0, pB1;
        #pragma unroll
        for (int c = 0; c < 4; ++c) {
            f32x4 mv0 = *reinterpret_cast<const f32x4*>(&mLs[kbase + 4 * hi + 8 * c]);
            f32x4 mv1 = *reinterpret_cast<const f32x4*>(&mLs[kbase + 32 + 4 * hi + 8 * c]);
            #pragma unroll
            for (int j = 0; j < 4; ++j) {
                pA0[4 * c + j] = mv0[j];  pA1[4 * c + j] = mv1[j];
                pB0[4 * c + j] = mv0[j];  pB1[4 * c + j] = mv1[j];
            }
        }

        // ---- QK^T for both q-blocks (kc shared)
        __builtin_amdgcn_s_setprio(1);
        #pragma unroll
        for (int ds = 0; ds < 4; ++ds) {
            pA0 = MFMA32(kc[ds],     qfA[ds], pA0);
            pA1 = MFMA32(kc[4 + ds], qfA[ds], pA1);
            pB0 = MFMA32(kc[ds],     qfB[ds], pB0);
            pB1 = MFMA32(kc[4 + ds], qfB[ds], pB1);
        }
        __builtin_amdgcn_s_setprio(0);

        // ---- lane-local softmax, two independent streams
        float pmA = pA0[0], pmB = pB0[0];
        #pragma unroll
        for (int r = 1; r < 16; ++r) { pmA = fmaxf(pmA, pA0[r]); pmB = fmaxf(pmB, pB0[r]); }
        #pragma unroll
        for (int r = 0; r < 16; ++r) { pmA = fmaxf(pmA, pA1[r]); pmB = fmaxf(pmB, pB1[r]); }
        pmA = fmaxf(pmA, __shfl_xor(pmA, 32));
        pmB = fmaxf(pmB, __shfl_xor(pmB, 32));

        if (!__all(pmA <= mA + 8.0f && pmB <= mB + 8.0f)) {   // defer-max (T13)
            const float nA = fmaxf(mA, pmA), nB = fmaxf(mB, pmB);
            const float sA = exp2f(mA - nA), sB = exp2f(mB - nB);
            mA = nA; mB = nB;
            lA *= sA; lB *= sB;
            #pragma unroll
            for (int r = 0; r < 16; ++r) {
                cA0[r] *= sA; cA1[r] *= sA;
                cB0[r] *= sB; cB1[r] *= sB;
            }
        }

        float psA = 0.f, psB = 0.f;
        #pragma unroll
        for (int r = 0; r < 16; ++r) {
            float eA = exp2f(pA0[r] - mA);  pA0[r] = eA;  psA += eA;
            float eB = exp2f(pB0[r] - mB);  pB0[r] = eB;  psB += eB;
        }
        #pragma unroll
        for (int r = 0; r < 16; ++r) {
            float eA = exp2f(pA1[r] - mA);  pA1[r] = eA;  psA += eA;
            float eB = exp2f(pB1[r] - mB);  pB1[r] = eB;  psB += eB;
        }
        psA += __shfl_xor(psA, 32);
        psB += __shfl_xor(psB, 32);
        lA += psA;  lB += psB;

        // ---- pack both P sets -> PV B-operands
        bf16x8 pbA[4], pbB[4];
        packP(pA0, pA1, pbA);
        packP(pB0, pB1, pbB);

        // ---- PV: V fragments shared by both q-blocks
        const char* VB = KB + 8192;
        __builtin_amdgcn_s_setprio(1);
        #pragma unroll
        for (int ks = 0; ks < 4; ++ks) {
            const int c = (ks * 32 + cb) ^ swz;
            bf16x8 vv0 = *reinterpret_cast<const bf16x8*>(VB + l31 * 128 + c);
            bf16x8 vv1 = *reinterpret_cast<const bf16x8*>(VB + (32 + l31) * 128 + c);
            cA0 = MFMA32(vv0, pbA[ks], cA0);
            cA1 = MFMA32(vv1, pbA[ks], cA1);
            cB0 = MFMA32(vv0, pbB[ks], cB0);
            cB1 = MFMA32(vv1, pbB[ks], cB1);
        }
        __builtin_amdgcn_s_setprio(0);
    };

    // ---- 2-phase pipelined main loop (1 barrier per tile)
    stage(0, 0);
    __syncthreads();
    for (int kt = 0; kt < 32; kt += 2) {
        stage(1, kt + 1);
        compute(0, kt * 64);
        __syncthreads();
        if (kt + 2 < 32) stage(0, kt + 2);
        compute(1, (kt + 1) * 64);
        __syncthreads();
    }

    // ---- epilogue: ctx^T C-layout -> out fp32 [b][s][h*64 + d]
    {
        const float invA = 1.0f / lA;
        float* op = out + (((size_t)(b * 2048 + qA)) << 10) + h * 64;
        #pragma unroll
        for (int c = 0; c < 4; ++c) {
            f32x4 s0v = {cA0[4 * c + 0] * invA, cA0[4 * c + 1] * invA,
                         cA0[4 * c + 2] * invA, cA0[4 * c + 3] * invA};
            f32x4 s1v = {cA1[4 * c + 0] * invA, cA1[4 * c + 1] * invA,
                         cA1[4 * c + 2] * invA, cA1[4 * c + 3] * invA};
            *reinterpret_cast<f32x4*>(op + 8 * c + 4 * hi)      = s0v;
            *reinterpret_cast<f32x4*>(op + 32 + 8 * c + 4 * hi) = s1v;
        }
        const float invB = 1.0f / lB;
        float* opB = op + ((size_t)32 << 10);   // +32 rows
        #pragma unroll
        for (int c = 0; c < 4; ++c) {
            f32x4 s0v = {cB0[4 * c + 0] * invB, cB0[4 * c + 1] * invB,
                         cB0[4 * c + 2] * invB, cB0[4 * c + 3] * invB};
            f32x4 s1v = {cB1[4 * c + 0] * invB, cB1[4 * c + 1] * invB,
                         cB1[4 * c + 2] * invB, cB1[4 * c + 3] * invB};
            *reinterpret_cast<f32x4*>(opB + 8 * c + 4 * hi)      = s0v;
            *reinterpret_cast<f32x4*>(opB + 32 + 8 * c + 4 * hi) = s1v;
        }
    }
}

// ---------------------------------------------------------------------------
extern "C" void kernel_launch(void* const* d_in, const int* in_sizes, int n_in,
                              void* d_out, int out_size, void* d_ws, size_t ws_size,
                              hipStream_t stream)
{
    const float* X    = (const float*)d_in[0];
    const float* mask = (const float*)d_in[1];
    const float* Wq   = (const float*)d_in[2];
    const float* bq   = (const float*)d_in[3];
    const float* Wk   = (const float*)d_in[4];
    const float* bk   = (const float*)d_in[5];
    const float* Wv   = (const float*)d_in[6];
    const float* bv   = (const float*)d_in[7];
    float* out = (float*)d_out;

    const size_t HEADS_ELEMS = (size_t)32 * 2048 * 64;
    __bf16* Qb = (__bf16*)d_ws;
    __bf16* Kb = Qb + HEADS_ELEMS;
    __bf16* Vb = Kb + HEADS_ELEMS;
    __bf16* Vt = Vb + HEADS_ELEMS;

    qkv_gemm<<<dim3(32, 8, 3), 256, 0, stream>>>(X, Wq, bq, Wk, bk, Wv, bv, Qb, Kb, Vb);
    v_transpose<<<dim3(32, 32), 256, 0, stream>>>(Vb, Vt);
    flash_attn<<<dim3(512), 128, 0, stream>>>(Qb, Kb, Vt, mask, out);
}